// Round 13
// baseline (1136.544 us; speedup 1.0000x reference)
//
#include <hip/hip_runtime.h>
#include <hip/hip_fp16.h>

#define N_NODES 500000
#define N_EDGES 8000000
#define W_BKT 512
#define LOG_W 9
#define NBKT 977                          // dst buckets = ceil(N/512)
#define SRC_MASK 0x7FFFFu
#define SCHUNK 32768
#define SBLK 512
#define S_BLOCKS ((N_EDGES + SCHUNK - 1) / SCHUNK)   // 245
#define NSEGB 8
#define SEGLENB 31                        // ceil(245/8)

typedef unsigned int uint;

__device__ __forceinline__ float leaky_f(float x) { return x > 0.0f ? x : 0.1f * x; }

// ===========================================================================
// k1: H[s][i] = {h0..h4, 0, 0, 0}  (32B record, read by p2a only)
// ===========================================================================
__global__ void k1_hx(const float* __restrict__ x,
                      const float* __restrict__ Wp,
                      const float* __restrict__ Ws,
                      const float* __restrict__ Wv,
                      float* __restrict__ H)
{
    __shared__ float sW[3][25][5];
    int t = threadIdx.x;
    if (t < 125) {
        sW[0][t / 5][t % 5] = Wp[t];
        sW[1][t / 5][t % 5] = Ws[t];
        sW[2][t / 5][t % 5] = Wv[t];
    }
    __syncthreads();
    int i = blockIdx.x * blockDim.x + t;
    if (i >= N_NODES) return;
    float xi[25];
#pragma unroll
    for (int k = 0; k < 25; ++k) xi[k] = x[i * 25 + k];
#pragma unroll
    for (int s = 0; s < 3; ++s) {
        float acc[5] = {0.f, 0.f, 0.f, 0.f, 0.f};
#pragma unroll
        for (int k = 0; k < 25; ++k)
#pragma unroll
            for (int c = 0; c < 5; ++c) acc[c] = fmaf(xi[k], sW[s][k][c], acc[c]);
        float* hp = H + ((size_t)s * N_NODES + i) * 8;
        *(float4*)hp = make_float4(acc[0], acc[1], acc[2], acc[3]);
        *(float4*)(hp + 4) = make_float4(acc[4], 0.f, 0.f, 0.f);
    }
}

// ===========================================================================
// Single-pass sort by dst-bucket (977 bins of 512 nodes), decoupled scans
// ===========================================================================

// per-block 977-bin histogram of dst>>9 (reads dst stream only, 32MB total)
__global__ void pS_hist(const int* __restrict__ ep, const int* __restrict__ es,
                        const int* __restrict__ ev, uint* __restrict__ bhB)
{
    int s = blockIdx.y;
    const int* ei = (s == 0) ? ep : ((s == 1) ? es : ev);
    const uint4* d4 = (const uint4*)((const uint*)ei + N_EDGES);
    __shared__ uint hist[NBKT];
    for (int b = threadIdx.x; b < NBKT; b += SBLK) hist[b] = 0;
    __syncthreads();
    int base4 = blockIdx.x * (SCHUNK / 4);
#pragma unroll
    for (int j = 0; j < SCHUNK / 4 / SBLK; ++j) {
        int g4 = base4 + j * SBLK + threadIdx.x;
        if (g4 < N_EDGES / 4) {
            uint4 d = d4[g4];
            atomicAdd(&hist[d.x >> LOG_W], 1u);
            atomicAdd(&hist[d.y >> LOG_W], 1u);
            atomicAdd(&hist[d.z >> LOG_W], 1u);
            atomicAdd(&hist[d.w >> LOG_W], 1u);
        }
    }
    __syncthreads();
    for (int b = threadIdx.x; b < NBKT; b += SBLK)
        bhB[((size_t)s * S_BLOCKS + blockIdx.x) * NBKT + b] = hist[b];
}

// segmented column scan of bhB (8 segs of 31 blocks), segment totals out
__global__ void kB1_segscan(uint* __restrict__ bhB, uint* __restrict__ segtotB)
{
    int bin = blockIdx.x * 256 + threadIdx.x;
    int seg = blockIdx.y, s = blockIdx.z;
    if (bin >= NBKT) return;
    uint* col = bhB + (size_t)s * S_BLOCKS * NBKT + bin;
    int b0 = seg * SEGLENB;
    int b1 = (b0 + SEGLENB < S_BLOCKS) ? b0 + SEGLENB : S_BLOCKS;
    uint run = 0;
    for (int blk = b0; blk < b1; ++blk) {
        size_t off = (size_t)blk * NBKT;
        uint c = col[off];
        col[off] = run;
        run += c;
    }
    segtotB[((size_t)s * NBKT + bin) * NSEGB + seg] = run;
}

// merged: counts = sum(segtot), exclusive scan -> baseB/bendB, segpreB
__global__ void kB_merge(const uint* __restrict__ segtotB,
                         uint* __restrict__ baseB, uint* __restrict__ bendB,
                         uint* __restrict__ segpreB)
{
    __shared__ uint buf[1024];
    int s = blockIdx.x, t = threadIdx.x;
    uint cnt = 0;
    if (t < NBKT) {
        const uint4* stp = (const uint4*)(segtotB + ((size_t)s * NBKT + t) * NSEGB);
        uint4 a = stp[0], b = stp[1];
        cnt = a.x + a.y + a.z + a.w + b.x + b.y + b.z + b.w;
    }
    buf[t] = cnt;
    __syncthreads();
    for (int off = 1; off < 1024; off <<= 1) {
        uint add = (t >= off) ? buf[t - off] : 0u;
        __syncthreads();
        buf[t] += add;
        __syncthreads();
    }
    if (t < NBKT) {
        uint ex = buf[t] - cnt;
        baseB[s * NBKT + t] = ex;
        bendB[s * NBKT + t] = ex + cnt;
        uint run = ex;
        const uint* st = segtotB + ((size_t)s * NBKT + t) * NSEGB;
#pragma unroll
        for (int seg = 0; seg < NSEGB; ++seg) {
            segpreB[((size_t)s * NSEGB + seg) * NBKT + t] = run;
            run += st[seg];
        }
    }
}

// scatter edges -> parts (packed (local_dst<<19)|src). Zero global atomics.
__global__ void pS_scatter(const int* __restrict__ ep, const int* __restrict__ es,
                           const int* __restrict__ ev, const uint* __restrict__ bhB,
                           const uint* __restrict__ segpreB, uint* __restrict__ parts)
{
    int s = blockIdx.y;
    const int* ei = (s == 0) ? ep : ((s == 1) ? es : ev);
    const uint4* s4 = (const uint4*)ei;
    const uint4* d4 = (const uint4*)((const uint*)ei + N_EDGES);
    uint* ps = parts + (size_t)s * N_EDGES;
    __shared__ uint hist[NBKT];
    __shared__ uint bbase[NBKT];
    const uint* bhrow = bhB + ((size_t)s * S_BLOCKS + blockIdx.x) * NBKT;
    const uint* segrow = segpreB + ((size_t)s * NSEGB + blockIdx.x / SEGLENB) * NBKT;
    for (int b = threadIdx.x; b < NBKT; b += SBLK) {
        bbase[b] = bhrow[b] + segrow[b];
        hist[b] = 0;
    }
    __syncthreads();
    int base4 = blockIdx.x * (SCHUNK / 4);
#pragma unroll
    for (int j = 0; j < SCHUNK / 4 / SBLK; ++j) {
        int g4 = base4 + j * SBLK + threadIdx.x;
        if (g4 < N_EDGES / 4) {
            uint4 sv = s4[g4];
            uint4 dv = d4[g4];
            {
                uint bkt = dv.x >> LOG_W, r = atomicAdd(&hist[bkt], 1u);
                ps[bbase[bkt] + r] = ((dv.x & (W_BKT - 1u)) << 19) | sv.x;
            }
            {
                uint bkt = dv.y >> LOG_W, r = atomicAdd(&hist[bkt], 1u);
                ps[bbase[bkt] + r] = ((dv.y & (W_BKT - 1u)) << 19) | sv.y;
            }
            {
                uint bkt = dv.z >> LOG_W, r = atomicAdd(&hist[bkt], 1u);
                ps[bbase[bkt] + r] = ((dv.z & (W_BKT - 1u)) << 19) | sv.z;
            }
            {
                uint bkt = dv.w >> LOG_W, r = atomicAdd(&hist[bkt], 1u);
                ps[bbase[bkt] + r] = ((dv.w & (W_BKT - 1u)) << 19) | sv.w;
            }
        }
    }
}

// ===========================================================================
// P2a: per-(bucket,set) degree -> G[s][node] = {h*rd x5 fp16, pad, rd fp32}
// ===========================================================================
__global__ void p2a_deg2(const uint* __restrict__ parts, const uint* __restrict__ baseB,
                         const uint* __restrict__ bendB, const float* __restrict__ H,
                         uint4* __restrict__ G)
{
    int b = blockIdx.x, s = blockIdx.y;
    __shared__ uint cnt[W_BKT];
    for (int t = threadIdx.x; t < W_BKT; t += 256) cnt[t] = 0;
    __syncthreads();
    uint st = baseB[s * NBKT + b], en = bendB[s * NBKT + b];
    const uint* pp = parts + (size_t)s * N_EDGES;
    for (uint i = st + threadIdx.x; i < en; i += 256) atomicAdd(&cnt[pp[i] >> 19], 1u);
    __syncthreads();
    int nb = b << LOG_W;
    const float* Hs = H + (size_t)s * N_NODES * 8;
    uint4* Gs = G + (size_t)s * N_NODES;
    for (int n = threadIdx.x; n < W_BKT; n += 256) {
        int node = nb + n;
        if (node < N_NODES) {
            float rd = rsqrtf(1.0f + (float)cnt[n]);
            const float* hp = Hs + (size_t)node * 8;
            float4 v = *(const float4*)hp;
            float h4 = hp[4];
            __half2 g01 = __floats2half2_rn(v.x * rd, v.y * rd);
            __half2 g23 = __floats2half2_rn(v.z * rd, v.w * rd);
            __half2 g45 = __floats2half2_rn(h4 * rd, 0.f);
            uint4 g;
            g.x = *reinterpret_cast<uint*>(&g01);
            g.y = *reinterpret_cast<uint*>(&g23);
            g.z = *reinterpret_cast<uint*>(&g45);
            g.w = __float_as_uint(rd);
            Gs[node] = g;
        }
    }
}

// ===========================================================================
// P2b fused: per 512-node bucket, 3 sets sequential into hin[512][15] LDS,
// then inline MLP -> out. Gathers are 16B fp16 records.
// ===========================================================================
#define LOADE(j, kk) \
    uint ld##j = (kk) >> 19; \
    uint4 g##j = Gs[(kk) & SRC_MASK]; \
    float r##j = rdd[ld##j];

#define ACCE(j) { \
    float2 f01 = __half22float2(*reinterpret_cast<const __half2*>(&g##j.x)); \
    float2 f23 = __half22float2(*reinterpret_cast<const __half2*>(&g##j.y)); \
    float2 f45 = __half22float2(*reinterpret_cast<const __half2*>(&g##j.z)); \
    float* A = accS + ld##j * 15; \
    atomicAdd(A + 0, f01.x * r##j); \
    atomicAdd(A + 1, f01.y * r##j); \
    atomicAdd(A + 2, f23.x * r##j); \
    atomicAdd(A + 3, f23.y * r##j); \
    atomicAdd(A + 4, f45.x * r##j); }

__global__ __launch_bounds__(512, 4) void p2b_fused(
    const uint* __restrict__ parts, const uint* __restrict__ baseB,
    const uint* __restrict__ bendB, const uint4* __restrict__ G,
    const float* __restrict__ bp, const float* __restrict__ bs,
    const float* __restrict__ bv,
    const float* __restrict__ pw1, const float* __restrict__ pb1,
    const float* __restrict__ pw2, const float* __restrict__ pb2,
    const float* __restrict__ cw1, const float* __restrict__ cb1,
    const float* __restrict__ cw2, const float* __restrict__ cb2,
    float* __restrict__ out)
{
    __shared__ float hin[W_BKT * 15];   // 30 KB
    __shared__ float rdd[W_BKT];        // 2 KB
    __shared__ float wts[272];          // 1.1 KB
    int b = blockIdx.x;
    int tid = threadIdx.x;
    for (int j = tid; j < 272; j += 512) {
        float v;
        if (j < 150) v = pw1[j];
        else if (j < 160) v = pb1[j - 150];
        else if (j < 210) v = pw2[j - 160];
        else if (j < 215) v = pb2[j - 210];
        else if (j < 240) v = cw1[j - 215];
        else if (j < 245) v = cb1[j - 240];
        else if (j < 255) v = cw2[j - 245];
        else if (j < 257) v = cb2[j - 255];
        else if (j < 262) v = bp[j - 257];
        else if (j < 267) v = bs[j - 262];
        else v = bv[j - 267];
        wts[j] = v;
    }
    int nb = b << LOG_W;

    for (int s = 0; s < 3; ++s) {
        const uint4* Gs = G + (size_t)s * N_NODES;
        float* accS = hin + s * 5;
        __syncthreads();   // wts ready (s=0) / prev set's atomics & rdd reads done

        const float* sb5 = &wts[257 + s * 5];
        for (int n = tid; n < W_BKT; n += 512) {
            int node = nb + n;
            float* a = accS + n * 15;
            if (node < N_NODES) {
                uint4 g = Gs[node];
                float rd = __uint_as_float(g.w);
                rdd[n] = rd;
                float2 f01 = __half22float2(*reinterpret_cast<const __half2*>(&g.x));
                float2 f23 = __half22float2(*reinterpret_cast<const __half2*>(&g.y));
                float2 f45 = __half22float2(*reinterpret_cast<const __half2*>(&g.z));
                a[0] = fmaf(f01.x, rd, sb5[0]);
                a[1] = fmaf(f01.y, rd, sb5[1]);
                a[2] = fmaf(f23.x, rd, sb5[2]);
                a[3] = fmaf(f23.y, rd, sb5[3]);
                a[4] = fmaf(f45.x, rd, sb5[4]);
            } else {
                rdd[n] = 0.f;
#pragma unroll
                for (int c = 0; c < 5; ++c) a[c] = 0.f;
            }
        }
        __syncthreads();

        uint st = baseB[s * NBKT + b], en = bendB[s * NBKT + b];
        const uint* pp = parts + (size_t)s * N_EDGES;
        uint i0 = st + tid;
        for (; i0 + 1536 < en; i0 += 2048) {
            uint k0 = pp[i0];
            uint k1 = pp[i0 + 512];
            uint k2 = pp[i0 + 1024];
            uint k3 = pp[i0 + 1536];
            LOADE(0, k0) LOADE(1, k1) LOADE(2, k2) LOADE(3, k3)
            ACCE(0) ACCE(1) ACCE(2) ACCE(3)
        }
        for (; i0 < en; i0 += 512) {
            uint kk = pp[i0];
            LOADE(9, kk)
            ACCE(9)
        }
    }
    __syncthreads();

    // fused MLP epilogue
    const float* W1 = wts;          const float* B1 = wts + 150;
    const float* W2 = wts + 160;    const float* B2 = wts + 210;
    const float* C1 = wts + 215;    const float* D1 = wts + 240;
    const float* C2 = wts + 245;    const float* D2 = wts + 255;
    for (int n = tid; n < W_BKT; n += 512) {
        int node = nb + n;
        if (node >= N_NODES) continue;
        float hv[15];
#pragma unroll
        for (int j = 0; j < 15; ++j) hv[j] = leaky_f(hin[n * 15 + j]);
        float h1[10];
#pragma unroll
        for (int o = 0; o < 10; ++o) h1[o] = B1[o];
#pragma unroll
        for (int k = 0; k < 15; ++k)
#pragma unroll
            for (int o = 0; o < 10; ++o) h1[o] = fmaf(hv[k], W1[k * 10 + o], h1[o]);
#pragma unroll
        for (int o = 0; o < 10; ++o) h1[o] = leaky_f(h1[o]);
        float h2[5];
#pragma unroll
        for (int o = 0; o < 5; ++o) h2[o] = B2[o];
#pragma unroll
        for (int k = 0; k < 10; ++k)
#pragma unroll
            for (int o = 0; o < 5; ++o) h2[o] = fmaf(h1[k], W2[k * 5 + o], h2[o]);
        float h3[5];
#pragma unroll
        for (int o = 0; o < 5; ++o) h3[o] = D1[o];
#pragma unroll
        for (int k = 0; k < 5; ++k)
#pragma unroll
            for (int o = 0; o < 5; ++o) h3[o] = fmaf(h2[k], C1[k * 5 + o], h3[o]);
#pragma unroll
        for (int o = 0; o < 5; ++o) h3[o] = leaky_f(h3[o]);
        float o0 = D2[0], o1 = D2[1];
#pragma unroll
        for (int k = 0; k < 5; ++k) {
            o0 = fmaf(h3[k], C2[k * 2 + 0], o0);
            o1 = fmaf(h3[k], C2[k * 2 + 1], o1);
        }
        out[(size_t)node * 2 + 0] = o0;
        out[(size_t)node * 2 + 1] = o1;
    }
}

// ===========================================================================
// FALLBACK PATH (round-0 pipeline, used only if ws too small — needs 66 MB)
// ===========================================================================
__global__ void k1_gemm_deginit(const float* __restrict__ x,
                                const float* __restrict__ Wp,
                                const float* __restrict__ Ws,
                                const float* __restrict__ Wv,
                                float* __restrict__ h, float* __restrict__ deg)
{
    __shared__ float sW[3][25][5];
    int t = threadIdx.x;
    if (t < 125) { sW[0][t/5][t%5]=Wp[t]; sW[1][t/5][t%5]=Ws[t]; sW[2][t/5][t%5]=Wv[t]; }
    __syncthreads();
    for (int i = blockIdx.x * blockDim.x + t; i < N_NODES; i += gridDim.x * blockDim.x) {
        float xi[25];
#pragma unroll
        for (int k = 0; k < 25; ++k) xi[k] = x[i * 25 + k];
#pragma unroll
        for (int s = 0; s < 3; ++s) {
            float acc[5] = {0.f,0.f,0.f,0.f,0.f};
#pragma unroll
            for (int k = 0; k < 25; ++k)
#pragma unroll
                for (int c = 0; c < 5; ++c) acc[c] = fmaf(xi[k], sW[s][k][c], acc[c]);
#pragma unroll
            for (int c = 0; c < 5; ++c) h[(s * N_NODES + i) * 5 + c] = acc[c];
            deg[s * N_NODES + i] = 1.0f;
        }
    }
}

__global__ void k2_degree(const int* __restrict__ ep, const int* __restrict__ es,
                          const int* __restrict__ ev, float* __restrict__ deg)
{
    long e = (long)blockIdx.x * blockDim.x + threadIdx.x;
    if (e >= 3L * N_EDGES) return;
    int s = (int)(e / N_EDGES);
    int i = (int)(e - (long)s * N_EDGES);
    const int* ei = (s == 0) ? ep : ((s == 1) ? es : ev);
    atomicAdd(&deg[s * N_NODES + ei[N_EDGES + i]], 1.0f);
}

__global__ void k3_accum_init(const float* __restrict__ h, const float* __restrict__ deg,
                              const float* __restrict__ bp, const float* __restrict__ bs,
                              const float* __restrict__ bv, float* __restrict__ accum)
{
    int i = blockIdx.x * blockDim.x + threadIdx.x;
    if (i >= N_NODES) return;
#pragma unroll
    for (int s = 0; s < 3; ++s) {
        const float* b = (s == 0) ? bp : ((s == 1) ? bs : bv);
        float inv = 1.0f / deg[s * N_NODES + i];
#pragma unroll
        for (int c = 0; c < 5; ++c)
            accum[(s * N_NODES + i) * 5 + c] = h[(s * N_NODES + i) * 5 + c] * inv + b[c];
    }
}

__global__ void k4_scatter(const int* __restrict__ ep, const int* __restrict__ es,
                           const int* __restrict__ ev, const float* __restrict__ h,
                           const float* __restrict__ deg, float* __restrict__ accum)
{
    long e = (long)blockIdx.x * blockDim.x + threadIdx.x;
    if (e >= 3L * N_EDGES) return;
    int s = (int)(e / N_EDGES);
    int i = (int)(e - (long)s * N_EDGES);
    const int* ei = (s == 0) ? ep : ((s == 1) ? es : ev);
    int src = ei[i];
    int dst = ei[N_EDGES + i];
    float norm = rsqrtf(deg[s * N_NODES + src] * deg[s * N_NODES + dst]);
    const float* hp = h + (size_t)(s * N_NODES + src) * 5;
    float* ap = accum + (size_t)(s * N_NODES + dst) * 5;
#pragma unroll
    for (int c = 0; c < 5; ++c) atomicAdd(&ap[c], hp[c] * norm);
}

__global__ void k5_mlp(const float* __restrict__ accum,
                       const float* __restrict__ pw1, const float* __restrict__ pb1,
                       const float* __restrict__ pw2, const float* __restrict__ pb2,
                       const float* __restrict__ cw1, const float* __restrict__ cb1,
                       const float* __restrict__ cw2, const float* __restrict__ cb2,
                       float* __restrict__ out)
{
    __shared__ float sw[257];
    for (int j = threadIdx.x; j < 257; j += blockDim.x) {
        float v;
        if (j < 150) v = pw1[j];
        else if (j < 160) v = pb1[j - 150];
        else if (j < 210) v = pw2[j - 160];
        else if (j < 215) v = pb2[j - 210];
        else if (j < 240) v = cw1[j - 215];
        else if (j < 245) v = cb1[j - 240];
        else if (j < 255) v = cw2[j - 245];
        else v = cb2[j - 255];
        sw[j] = v;
    }
    __syncthreads();
    const float* W1 = sw; const float* B1 = sw + 150; const float* W2 = sw + 160;
    const float* B2 = sw + 210; const float* C1 = sw + 215; const float* D1 = sw + 240;
    const float* C2 = sw + 245; const float* D2 = sw + 255;
    int i = blockIdx.x * blockDim.x + threadIdx.x;
    if (i >= N_NODES) return;
    float hin[15];
#pragma unroll
    for (int s = 0; s < 3; ++s)
#pragma unroll
        for (int c = 0; c < 5; ++c)
            hin[s * 5 + c] = leaky_f(accum[(size_t)(s * N_NODES + i) * 5 + c]);
    float h1[10];
#pragma unroll
    for (int o = 0; o < 10; ++o) h1[o] = B1[o];
#pragma unroll
    for (int k = 0; k < 15; ++k)
#pragma unroll
        for (int o = 0; o < 10; ++o) h1[o] = fmaf(hin[k], W1[k * 10 + o], h1[o]);
#pragma unroll
    for (int o = 0; o < 10; ++o) h1[o] = leaky_f(h1[o]);
    float h2[5];
#pragma unroll
    for (int o = 0; o < 5; ++o) h2[o] = B2[o];
#pragma unroll
    for (int k = 0; k < 10; ++k)
#pragma unroll
        for (int o = 0; o < 5; ++o) h2[o] = fmaf(h1[k], W2[k * 5 + o], h2[o]);
    float h3[5];
#pragma unroll
    for (int o = 0; o < 5; ++o) h3[o] = D1[o];
#pragma unroll
    for (int k = 0; k < 5; ++k)
#pragma unroll
        for (int o = 0; o < 5; ++o) h3[o] = fmaf(h2[k], C1[k * 5 + o], h3[o]);
#pragma unroll
    for (int o = 0; o < 5; ++o) h3[o] = leaky_f(h3[o]);
    float o0 = D2[0], o1 = D2[1];
#pragma unroll
    for (int k = 0; k < 5; ++k) {
        o0 = fmaf(h3[k], C2[k * 2 + 0], o0);
        o1 = fmaf(h3[k], C2[k * 2 + 1], o1);
    }
    out[(size_t)i * 2 + 0] = o0;
    out[(size_t)i * 2 + 1] = o1;
}

// ===========================================================================

extern "C" void kernel_launch(void* const* d_in, const int* in_sizes, int n_in,
                              void* d_out, int out_size, void* d_ws, size_t ws_size,
                              hipStream_t stream)
{
    const float* x   = (const float*)d_in[0];
    const int*   ep  = (const int*)d_in[1];
    const int*   es  = (const int*)d_in[2];
    const int*   ev  = (const int*)d_in[3];
    const float* Wp  = (const float*)d_in[4];
    const float* bp  = (const float*)d_in[5];
    const float* Ws  = (const float*)d_in[6];
    const float* bs  = (const float*)d_in[7];
    const float* Wv  = (const float*)d_in[8];
    const float* bv  = (const float*)d_in[9];
    const float* pw1 = (const float*)d_in[10];
    const float* pb1 = (const float*)d_in[11];
    const float* pw2 = (const float*)d_in[12];
    const float* pb2 = (const float*)d_in[13];
    const float* cw1 = (const float*)d_in[14];
    const float* cb1 = (const float*)d_in[15];
    const float* cw2 = (const float*)d_in[16];
    const float* cb2 = (const float*)d_in[17];
    float* out = (float*)d_out;

    int gridN = (N_NODES + 255) / 256;

    const size_t H_BYTES    = 3ULL * N_NODES * 8 * 4;        // 48.0 MB
    const size_t P_BYTES    = 3ULL * N_EDGES * 4;            // 96.0 MB (parts)
    const size_t G_BYTES    = 3ULL * N_NODES * 16;           // 24.0 MB
    const size_t BHB_ELEMS  = 3ULL * S_BLOCKS * NBKT;        // 2.87 MB
    const size_t SEGT_ELEMS = 3ULL * NBKT * NSEGB;
    const size_t SEGP_ELEMS = 3ULL * NSEGB * NBKT;
    const size_t META       = (BHB_ELEMS + SEGT_ELEMS + SEGP_ELEMS + 6ULL * NBKT) * 4 + 1024;
    const size_t NEED = H_BYTES + P_BYTES + G_BYTES + META;

    if (ws_size >= NEED) {
        float* H      = (float*)d_ws;
        uint*  parts  = (uint*)((char*)d_ws + H_BYTES);
        uint4* G      = (uint4*)(parts + 3ULL * N_EDGES);
        uint*  bhB    = (uint*)((char*)G + G_BYTES);
        uint*  segtotB = bhB + BHB_ELEMS;                // uint4-aligned offsets
        uint*  segpreB = segtotB + SEGT_ELEMS;
        uint*  baseB  = segpreB + SEGP_ELEMS;
        uint*  bendB  = baseB + 3 * NBKT;

        dim3 gridS(S_BLOCKS, 3);
        dim3 gridB1((NBKT + 255) / 256, NSEGB, 3);
        dim3 gridP2(NBKT, 3);

        k1_hx<<<gridN, 256, 0, stream>>>(x, Wp, Ws, Wv, H);
        pS_hist<<<gridS, SBLK, 0, stream>>>(ep, es, ev, bhB);
        kB1_segscan<<<gridB1, 256, 0, stream>>>(bhB, segtotB);
        kB_merge<<<3, 1024, 0, stream>>>(segtotB, baseB, bendB, segpreB);
        pS_scatter<<<gridS, SBLK, 0, stream>>>(ep, es, ev, bhB, segpreB, parts);
        p2a_deg2<<<gridP2, 256, 0, stream>>>(parts, baseB, bendB, H, G);
        p2b_fused<<<NBKT, 512, 0, stream>>>(parts, baseB, bendB, G,
                                            bp, bs, bv,
                                            pw1, pb1, pw2, pb2,
                                            cw1, cb1, cw2, cb2, out);
    } else {
        // minimal fallback (round-0 pipeline, needs 66 MB)
        float* ws    = (float*)d_ws;
        float* h     = ws;
        float* deg   = h + 3L * N_NODES * 5;
        float* accum = deg + 3L * N_NODES;

        const int BLK = 256;
        int gridNf = (N_NODES + BLK - 1) / BLK;
        long totalE = 3L * N_EDGES;
        int gridE = (int)((totalE + BLK - 1) / BLK);

        k1_gemm_deginit<<<gridNf, BLK, 0, stream>>>(x, Wp, Ws, Wv, h, deg);
        k2_degree<<<gridE, BLK, 0, stream>>>(ep, es, ev, deg);
        k3_accum_init<<<gridNf, BLK, 0, stream>>>(h, deg, bp, bs, bv, accum);
        k4_scatter<<<gridE, BLK, 0, stream>>>(ep, es, ev, h, deg, accum);
        k5_mlp<<<gridNf, BLK, 0, stream>>>(accum, pw1, pb1, pw2, pb2, cw1, cb1, cw2, cb2, out);
    }
}

// Round 14
// 1040.991 us; speedup vs baseline: 1.0918x; 1.0918x over previous
//
#include <hip/hip_runtime.h>
#include <hip/hip_fp16.h>

#define N_NODES 500000
#define N_EDGES 8000000
#define W_BKT 1024
#define LOG_W 10
#define NBKT 489                          // dst buckets = ceil(N/1024)
#define NPAD (NBKT * W_BKT)
#define SRC_MASK 0x7FFFFu
#define SCHUNK 32768
#define SBLK 512
#define S_BLOCKS ((N_EDGES + SCHUNK - 1) / SCHUNK)   // 245
#define NSEGB 8
#define SEGLENB 31                        // ceil(245/8)

typedef unsigned int uint;

__device__ __forceinline__ float leaky_f(float x) { return x > 0.0f ? x : 0.1f * x; }

// ===========================================================================
// k1: H[s][i] = {h0..h4, 0, 0, 0}  (32B record, read by p2a only)
// ===========================================================================
__global__ void k1_hx(const float* __restrict__ x,
                      const float* __restrict__ Wp,
                      const float* __restrict__ Ws,
                      const float* __restrict__ Wv,
                      float* __restrict__ H)
{
    __shared__ float sW[3][25][5];
    int t = threadIdx.x;
    if (t < 125) {
        sW[0][t / 5][t % 5] = Wp[t];
        sW[1][t / 5][t % 5] = Ws[t];
        sW[2][t / 5][t % 5] = Wv[t];
    }
    __syncthreads();
    int i = blockIdx.x * blockDim.x + t;
    if (i >= N_NODES) return;
    float xi[25];
#pragma unroll
    for (int k = 0; k < 25; ++k) xi[k] = x[i * 25 + k];
#pragma unroll
    for (int s = 0; s < 3; ++s) {
        float acc[5] = {0.f, 0.f, 0.f, 0.f, 0.f};
#pragma unroll
        for (int k = 0; k < 25; ++k)
#pragma unroll
            for (int c = 0; c < 5; ++c) acc[c] = fmaf(xi[k], sW[s][k][c], acc[c]);
        float* hp = H + ((size_t)s * N_NODES + i) * 8;
        *(float4*)hp = make_float4(acc[0], acc[1], acc[2], acc[3]);
        *(float4*)(hp + 4) = make_float4(acc[4], 0.f, 0.f, 0.f);
    }
}

// ===========================================================================
// Single-pass sort by dst-bucket (489 bins of 1024 nodes), decoupled scans
// ===========================================================================

// per-block 489-bin histogram of dst>>10 (reads dst stream only)
__global__ void pS_hist(const int* __restrict__ ep, const int* __restrict__ es,
                        const int* __restrict__ ev, uint* __restrict__ bhB)
{
    int s = blockIdx.y;
    const int* ei = (s == 0) ? ep : ((s == 1) ? es : ev);
    const uint4* d4 = (const uint4*)((const uint*)ei + N_EDGES);
    __shared__ uint hist[NBKT];
    if (threadIdx.x < NBKT) hist[threadIdx.x] = 0;
    __syncthreads();
    int base4 = blockIdx.x * (SCHUNK / 4);
#pragma unroll
    for (int j = 0; j < SCHUNK / 4 / SBLK; ++j) {
        int g4 = base4 + j * SBLK + threadIdx.x;
        if (g4 < N_EDGES / 4) {
            uint4 d = d4[g4];
            atomicAdd(&hist[d.x >> LOG_W], 1u);
            atomicAdd(&hist[d.y >> LOG_W], 1u);
            atomicAdd(&hist[d.z >> LOG_W], 1u);
            atomicAdd(&hist[d.w >> LOG_W], 1u);
        }
    }
    __syncthreads();
    if (threadIdx.x < NBKT)
        bhB[((size_t)s * S_BLOCKS + blockIdx.x) * NBKT + threadIdx.x] = hist[threadIdx.x];
}

// segmented column scan of bhB (8 segs of 31 blocks), segment totals out
__global__ void kB1_segscan(uint* __restrict__ bhB, uint* __restrict__ segtotB)
{
    int bin = blockIdx.x * 256 + threadIdx.x;
    int seg = blockIdx.y, s = blockIdx.z;
    if (bin >= NBKT) return;
    uint* col = bhB + (size_t)s * S_BLOCKS * NBKT + bin;
    int b0 = seg * SEGLENB;
    int b1 = (b0 + SEGLENB < S_BLOCKS) ? b0 + SEGLENB : S_BLOCKS;
    uint run = 0;
    for (int blk = b0; blk < b1; ++blk) {
        size_t off = (size_t)blk * NBKT;
        uint c = col[off];
        col[off] = run;
        run += c;
    }
    segtotB[((size_t)s * NBKT + bin) * NSEGB + seg] = run;
}

// per-bucket counts = sum of 8 segment totals
__global__ void kB2_counts(const uint* __restrict__ segtotB, uint* __restrict__ countsB)
{
    int bin = blockIdx.x * 256 + threadIdx.x;
    int s = blockIdx.y;
    if (bin >= NBKT) return;
    const uint4* stp = (const uint4*)(segtotB + ((size_t)s * NBKT + bin) * NSEGB);
    uint4 a = stp[0], b = stp[1];
    countsB[s * NBKT + bin] = a.x + a.y + a.z + a.w + b.x + b.y + b.z + b.w;
}

// exclusive scan of 489 bucket counts -> baseB/bendB
__global__ void scanB(const uint* __restrict__ countsB,
                      uint* __restrict__ baseB, uint* __restrict__ bendB)
{
    __shared__ uint buf[512];
    int s = blockIdx.x, t = threadIdx.x;
    uint v = (t < NBKT) ? countsB[s * NBKT + t] : 0u;
    buf[t] = v;
    __syncthreads();
    for (int off = 1; off < 512; off <<= 1) {
        uint add = (t >= off) ? buf[t - off] : 0u;
        __syncthreads();
        buf[t] += add;
        __syncthreads();
    }
    if (t < NBKT) {
        uint ex = buf[t] - v;
        baseB[s * NBKT + t] = ex;
        bendB[s * NBKT + t] = ex + v;
    }
}

// segpreB = baseB + cross-segment prefix
__global__ void kB3_segpre(const uint* __restrict__ segtotB,
                           const uint* __restrict__ baseB, uint* __restrict__ segpreB)
{
    int bin = blockIdx.x * 256 + threadIdx.x;
    int s = blockIdx.y;
    if (bin >= NBKT) return;
    uint run = baseB[s * NBKT + bin];
    const uint* st = segtotB + ((size_t)s * NBKT + bin) * NSEGB;
#pragma unroll
    for (int seg = 0; seg < NSEGB; ++seg) {
        segpreB[((size_t)s * NSEGB + seg) * NBKT + bin] = run;
        run += st[seg];
    }
}

// scatter edges -> parts (packed (local_dst10<<19)|src). Zero global atomics.
__global__ void pS_scatter(const int* __restrict__ ep, const int* __restrict__ es,
                           const int* __restrict__ ev, const uint* __restrict__ bhB,
                           const uint* __restrict__ segpreB, uint* __restrict__ parts)
{
    int s = blockIdx.y;
    const int* ei = (s == 0) ? ep : ((s == 1) ? es : ev);
    const uint4* s4 = (const uint4*)ei;
    const uint4* d4 = (const uint4*)((const uint*)ei + N_EDGES);
    uint* ps = parts + (size_t)s * N_EDGES;
    __shared__ uint hist[NBKT];
    __shared__ uint bbase[NBKT];
    const uint* bhrow = bhB + ((size_t)s * S_BLOCKS + blockIdx.x) * NBKT;
    const uint* segrow = segpreB + ((size_t)s * NSEGB + blockIdx.x / SEGLENB) * NBKT;
    if (threadIdx.x < NBKT) {
        bbase[threadIdx.x] = bhrow[threadIdx.x] + segrow[threadIdx.x];
        hist[threadIdx.x] = 0;
    }
    __syncthreads();
    int base4 = blockIdx.x * (SCHUNK / 4);
#pragma unroll
    for (int j = 0; j < SCHUNK / 4 / SBLK; ++j) {
        int g4 = base4 + j * SBLK + threadIdx.x;
        if (g4 < N_EDGES / 4) {
            uint4 sv = s4[g4];
            uint4 dv = d4[g4];
            {
                uint bkt = dv.x >> LOG_W, r = atomicAdd(&hist[bkt], 1u);
                ps[bbase[bkt] + r] = ((dv.x & (W_BKT - 1u)) << 19) | sv.x;
            }
            {
                uint bkt = dv.y >> LOG_W, r = atomicAdd(&hist[bkt], 1u);
                ps[bbase[bkt] + r] = ((dv.y & (W_BKT - 1u)) << 19) | sv.y;
            }
            {
                uint bkt = dv.z >> LOG_W, r = atomicAdd(&hist[bkt], 1u);
                ps[bbase[bkt] + r] = ((dv.z & (W_BKT - 1u)) << 19) | sv.z;
            }
            {
                uint bkt = dv.w >> LOG_W, r = atomicAdd(&hist[bkt], 1u);
                ps[bbase[bkt] + r] = ((dv.w & (W_BKT - 1u)) << 19) | sv.w;
            }
        }
    }
}

// ===========================================================================
// P2a: per-(bucket,set) degree -> G[s][node] = {h*rd x5 fp16, pad, rd fp32}
// ===========================================================================
__global__ void p2a_deg2(const uint* __restrict__ parts, const uint* __restrict__ baseB,
                         const uint* __restrict__ bendB, const float* __restrict__ H,
                         uint4* __restrict__ G)
{
    int b = blockIdx.x, s = blockIdx.y;
    __shared__ uint cnt[W_BKT];
    for (int t = threadIdx.x; t < W_BKT; t += 256) cnt[t] = 0;
    __syncthreads();
    uint st = baseB[s * NBKT + b], en = bendB[s * NBKT + b];
    const uint* pp = parts + (size_t)s * N_EDGES;
    for (uint i = st + threadIdx.x; i < en; i += 256) atomicAdd(&cnt[pp[i] >> 19], 1u);
    __syncthreads();
    int nb = b << LOG_W;
    const float* Hs = H + (size_t)s * N_NODES * 8;
    uint4* Gs = G + (size_t)s * N_NODES;
    for (int n = threadIdx.x; n < W_BKT; n += 256) {
        int node = nb + n;
        if (node < N_NODES) {
            float rd = rsqrtf(1.0f + (float)cnt[n]);
            const float* hp = Hs + (size_t)node * 8;
            float4 v = *(const float4*)hp;
            float h4 = hp[4];
            __half2 g01 = __floats2half2_rn(v.x * rd, v.y * rd);
            __half2 g23 = __floats2half2_rn(v.z * rd, v.w * rd);
            __half2 g45 = __floats2half2_rn(h4 * rd, 0.f);
            uint4 g;
            g.x = *reinterpret_cast<uint*>(&g01);
            g.y = *reinterpret_cast<uint*>(&g23);
            g.z = *reinterpret_cast<uint*>(&g45);
            g.w = __float_as_uint(rd);
            Gs[node] = g;
        }
    }
}

// ===========================================================================
// P2b: per-bucket LDS aggregation, all 3 sets in one dispatch (489x3 grid),
// 16B fp16 gathers, 8-deep strided ILP. (round-10 structure, G-only init)
// ===========================================================================
#define LOADE(j, kk) \
    uint ld##j = (kk) >> 19; \
    uint4 g##j = Gs[(kk) & SRC_MASK]; \
    float r##j = rdd[ld##j];

#define ACCE(j) { \
    float2 f01 = __half22float2(*reinterpret_cast<const __half2*>(&g##j.x)); \
    float2 f23 = __half22float2(*reinterpret_cast<const __half2*>(&g##j.y)); \
    float2 f45 = __half22float2(*reinterpret_cast<const __half2*>(&g##j.z)); \
    float* A = &acc[ld##j * 5]; \
    atomicAdd(A + 0, f01.x * r##j); \
    atomicAdd(A + 1, f01.y * r##j); \
    atomicAdd(A + 2, f23.x * r##j); \
    atomicAdd(A + 3, f23.y * r##j); \
    atomicAdd(A + 4, f45.x * r##j); }

__global__ __launch_bounds__(512, 4) void p2b_agg2(
    const uint* __restrict__ parts, const uint* __restrict__ baseB,
    const uint* __restrict__ bendB, const uint4* __restrict__ G,
    const float* __restrict__ bp, const float* __restrict__ bs,
    const float* __restrict__ bv, float* __restrict__ accum)
{
    __shared__ float acc[W_BKT * 5];    // 20 KB
    __shared__ float rdd[W_BKT];        // 4 KB
    __shared__ float sb5[5];
    int b = blockIdx.x, s = blockIdx.y;
    int tid = threadIdx.x;
    const float* bias = (s == 0) ? bp : ((s == 1) ? bs : bv);
    if (tid < 5) sb5[tid] = bias[tid];
    int nb = b << LOG_W;
    const uint4* Gs = G + (size_t)s * N_NODES;
    __syncthreads();

    // self-loop + bias init from G: acc = (h*rd)_fp16 * rd + bias
    for (int n = tid; n < W_BKT; n += 512) {
        int node = nb + n;
        float* a = &acc[n * 5];
        if (node < N_NODES) {
            uint4 g = Gs[node];
            float rd = __uint_as_float(g.w);
            rdd[n] = rd;
            float2 f01 = __half22float2(*reinterpret_cast<const __half2*>(&g.x));
            float2 f23 = __half22float2(*reinterpret_cast<const __half2*>(&g.y));
            float2 f45 = __half22float2(*reinterpret_cast<const __half2*>(&g.z));
            a[0] = fmaf(f01.x, rd, sb5[0]);
            a[1] = fmaf(f01.y, rd, sb5[1]);
            a[2] = fmaf(f23.x, rd, sb5[2]);
            a[3] = fmaf(f23.y, rd, sb5[3]);
            a[4] = fmaf(f45.x, rd, sb5[4]);
        } else {
            rdd[n] = 0.f;
#pragma unroll
            for (int c = 0; c < 5; ++c) a[c] = 0.f;
        }
    }
    __syncthreads();

    uint st = baseB[s * NBKT + b], en = bendB[s * NBKT + b];
    const uint* pp = parts + (size_t)s * N_EDGES;
    uint span = en - st;
    uint nfull = (span / 4096u) * 4096u;
    for (uint i0 = st + tid; i0 < st + nfull; i0 += 4096u) {
        uint k0 = pp[i0];
        uint k1 = pp[i0 + 512];
        uint k2 = pp[i0 + 1024];
        uint k3 = pp[i0 + 1536];
        uint k4 = pp[i0 + 2048];
        uint k5 = pp[i0 + 2560];
        uint k6 = pp[i0 + 3072];
        uint k7 = pp[i0 + 3584];
        LOADE(0, k0) LOADE(1, k1) LOADE(2, k2) LOADE(3, k3)
        LOADE(4, k4) LOADE(5, k5) LOADE(6, k6) LOADE(7, k7)
        ACCE(0) ACCE(1) ACCE(2) ACCE(3) ACCE(4) ACCE(5) ACCE(6) ACCE(7)
    }
    for (uint i = st + nfull + tid; i < en; i += 512u) {
        uint kk = pp[i];
        LOADE(9, kk)
        ACCE(9)
    }
    __syncthreads();

    float* op = accum + ((size_t)s * NPAD + nb) * 5;
    for (int t = tid; t < W_BKT * 5; t += 512) op[t] = acc[t];
}

// ===========================================================================
// K6: per-node fused MLP epilogue
// ===========================================================================
__global__ void k6_mlp(const float* __restrict__ accum,
                       const float* __restrict__ pw1, const float* __restrict__ pb1,
                       const float* __restrict__ pw2, const float* __restrict__ pb2,
                       const float* __restrict__ cw1, const float* __restrict__ cb1,
                       const float* __restrict__ cw2, const float* __restrict__ cb2,
                       float* __restrict__ out)
{
    __shared__ float sw[257];
    for (int j = threadIdx.x; j < 257; j += blockDim.x) {
        float v;
        if (j < 150) v = pw1[j];
        else if (j < 160) v = pb1[j - 150];
        else if (j < 210) v = pw2[j - 160];
        else if (j < 215) v = pb2[j - 210];
        else if (j < 240) v = cw1[j - 215];
        else if (j < 245) v = cb1[j - 240];
        else if (j < 255) v = cw2[j - 245];
        else v = cb2[j - 255];
        sw[j] = v;
    }
    __syncthreads();
    const float* W1 = sw;         const float* B1 = sw + 150;
    const float* W2 = sw + 160;   const float* B2 = sw + 210;
    const float* C1 = sw + 215;   const float* D1 = sw + 240;
    const float* C2 = sw + 245;   const float* D2 = sw + 255;

    int i = blockIdx.x * blockDim.x + threadIdx.x;
    if (i >= N_NODES) return;

    float hin[15];
#pragma unroll
    for (int s = 0; s < 3; ++s) {
        const float* ap = accum + ((size_t)s * NPAD + i) * 5;
#pragma unroll
        for (int c = 0; c < 5; ++c) hin[s * 5 + c] = leaky_f(ap[c]);
    }
    float h1[10];
#pragma unroll
    for (int o = 0; o < 10; ++o) h1[o] = B1[o];
#pragma unroll
    for (int k = 0; k < 15; ++k)
#pragma unroll
        for (int o = 0; o < 10; ++o) h1[o] = fmaf(hin[k], W1[k * 10 + o], h1[o]);
#pragma unroll
    for (int o = 0; o < 10; ++o) h1[o] = leaky_f(h1[o]);
    float h2[5];
#pragma unroll
    for (int o = 0; o < 5; ++o) h2[o] = B2[o];
#pragma unroll
    for (int k = 0; k < 10; ++k)
#pragma unroll
        for (int o = 0; o < 5; ++o) h2[o] = fmaf(h1[k], W2[k * 5 + o], h2[o]);
    float h3[5];
#pragma unroll
    for (int o = 0; o < 5; ++o) h3[o] = D1[o];
#pragma unroll
    for (int k = 0; k < 5; ++k)
#pragma unroll
        for (int o = 0; o < 5; ++o) h3[o] = fmaf(h2[k], C1[k * 5 + o], h3[o]);
#pragma unroll
    for (int o = 0; o < 5; ++o) h3[o] = leaky_f(h3[o]);
    float o0 = D2[0], o1 = D2[1];
#pragma unroll
    for (int k = 0; k < 5; ++k) {
        o0 = fmaf(h3[k], C2[k * 2 + 0], o0);
        o1 = fmaf(h3[k], C2[k * 2 + 1], o1);
    }
    out[(size_t)i * 2 + 0] = o0;
    out[(size_t)i * 2 + 1] = o1;
}

// ===========================================================================
// FALLBACK PATH (round-0 pipeline, used only if ws too small — needs 66 MB)
// ===========================================================================
__global__ void k1_gemm_deginit(const float* __restrict__ x,
                                const float* __restrict__ Wp,
                                const float* __restrict__ Ws,
                                const float* __restrict__ Wv,
                                float* __restrict__ h, float* __restrict__ deg)
{
    __shared__ float sW[3][25][5];
    int t = threadIdx.x;
    if (t < 125) { sW[0][t/5][t%5]=Wp[t]; sW[1][t/5][t%5]=Ws[t]; sW[2][t/5][t%5]=Wv[t]; }
    __syncthreads();
    for (int i = blockIdx.x * blockDim.x + t; i < N_NODES; i += gridDim.x * blockDim.x) {
        float xi[25];
#pragma unroll
        for (int k = 0; k < 25; ++k) xi[k] = x[i * 25 + k];
#pragma unroll
        for (int s = 0; s < 3; ++s) {
            float acc[5] = {0.f,0.f,0.f,0.f,0.f};
#pragma unroll
            for (int k = 0; k < 25; ++k)
#pragma unroll
                for (int c = 0; c < 5; ++c) acc[c] = fmaf(xi[k], sW[s][k][c], acc[c]);
#pragma unroll
            for (int c = 0; c < 5; ++c) h[(s * N_NODES + i) * 5 + c] = acc[c];
            deg[s * N_NODES + i] = 1.0f;
        }
    }
}

__global__ void k2_degree(const int* __restrict__ ep, const int* __restrict__ es,
                          const int* __restrict__ ev, float* __restrict__ deg)
{
    long e = (long)blockIdx.x * blockDim.x + threadIdx.x;
    if (e >= 3L * N_EDGES) return;
    int s = (int)(e / N_EDGES);
    int i = (int)(e - (long)s * N_EDGES);
    const int* ei = (s == 0) ? ep : ((s == 1) ? es : ev);
    atomicAdd(&deg[s * N_NODES + ei[N_EDGES + i]], 1.0f);
}

__global__ void k3_accum_init(const float* __restrict__ h, const float* __restrict__ deg,
                              const float* __restrict__ bp, const float* __restrict__ bs,
                              const float* __restrict__ bv, float* __restrict__ accum)
{
    int i = blockIdx.x * blockDim.x + threadIdx.x;
    if (i >= N_NODES) return;
#pragma unroll
    for (int s = 0; s < 3; ++s) {
        const float* b = (s == 0) ? bp : ((s == 1) ? bs : bv);
        float inv = 1.0f / deg[s * N_NODES + i];
#pragma unroll
        for (int c = 0; c < 5; ++c)
            accum[(s * N_NODES + i) * 5 + c] = h[(s * N_NODES + i) * 5 + c] * inv + b[c];
    }
}

__global__ void k4_scatter(const int* __restrict__ ep, const int* __restrict__ es,
                           const int* __restrict__ ev, const float* __restrict__ h,
                           const float* __restrict__ deg, float* __restrict__ accum)
{
    long e = (long)blockIdx.x * blockDim.x + threadIdx.x;
    if (e >= 3L * N_EDGES) return;
    int s = (int)(e / N_EDGES);
    int i = (int)(e - (long)s * N_EDGES);
    const int* ei = (s == 0) ? ep : ((s == 1) ? es : ev);
    int src = ei[i];
    int dst = ei[N_EDGES + i];
    float norm = rsqrtf(deg[s * N_NODES + src] * deg[s * N_NODES + dst]);
    const float* hp = h + (size_t)(s * N_NODES + src) * 5;
    float* ap = accum + (size_t)(s * N_NODES + dst) * 5;
#pragma unroll
    for (int c = 0; c < 5; ++c) atomicAdd(&ap[c], hp[c] * norm);
}

__global__ void k5_mlp(const float* __restrict__ accum,
                       const float* __restrict__ pw1, const float* __restrict__ pb1,
                       const float* __restrict__ pw2, const float* __restrict__ pb2,
                       const float* __restrict__ cw1, const float* __restrict__ cb1,
                       const float* __restrict__ cw2, const float* __restrict__ cb2,
                       float* __restrict__ out)
{
    __shared__ float sw[257];
    for (int j = threadIdx.x; j < 257; j += blockDim.x) {
        float v;
        if (j < 150) v = pw1[j];
        else if (j < 160) v = pb1[j - 150];
        else if (j < 210) v = pw2[j - 160];
        else if (j < 215) v = pb2[j - 210];
        else if (j < 240) v = cw1[j - 215];
        else if (j < 245) v = cb1[j - 240];
        else if (j < 255) v = cw2[j - 245];
        else v = cb2[j - 255];
        sw[j] = v;
    }
    __syncthreads();
    const float* W1 = sw; const float* B1 = sw + 150; const float* W2 = sw + 160;
    const float* B2 = sw + 210; const float* C1 = sw + 215; const float* D1 = sw + 240;
    const float* C2 = sw + 245; const float* D2 = sw + 255;
    int i = blockIdx.x * blockDim.x + threadIdx.x;
    if (i >= N_NODES) return;
    float hin[15];
#pragma unroll
    for (int s = 0; s < 3; ++s)
#pragma unroll
        for (int c = 0; c < 5; ++c)
            hin[s * 5 + c] = leaky_f(accum[(size_t)(s * N_NODES + i) * 5 + c]);
    float h1[10];
#pragma unroll
    for (int o = 0; o < 10; ++o) h1[o] = B1[o];
#pragma unroll
    for (int k = 0; k < 15; ++k)
#pragma unroll
        for (int o = 0; o < 10; ++o) h1[o] = fmaf(hin[k], W1[k * 10 + o], h1[o]);
#pragma unroll
    for (int o = 0; o < 10; ++o) h1[o] = leaky_f(h1[o]);
    float h2[5];
#pragma unroll
    for (int o = 0; o < 5; ++o) h2[o] = B2[o];
#pragma unroll
    for (int k = 0; k < 10; ++k)
#pragma unroll
        for (int o = 0; o < 5; ++o) h2[o] = fmaf(h1[k], W2[k * 5 + o], h2[o]);
    float h3[5];
#pragma unroll
    for (int o = 0; o < 5; ++o) h3[o] = D1[o];
#pragma unroll
    for (int k = 0; k < 5; ++k)
#pragma unroll
        for (int o = 0; o < 5; ++o) h3[o] = fmaf(h2[k], C1[k * 5 + o], h3[o]);
#pragma unroll
    for (int o = 0; o < 5; ++o) h3[o] = leaky_f(h3[o]);
    float o0 = D2[0], o1 = D2[1];
#pragma unroll
    for (int k = 0; k < 5; ++k) {
        o0 = fmaf(h3[k], C2[k * 2 + 0], o0);
        o1 = fmaf(h3[k], C2[k * 2 + 1], o1);
    }
    out[(size_t)i * 2 + 0] = o0;
    out[(size_t)i * 2 + 1] = o1;
}

// ===========================================================================

extern "C" void kernel_launch(void* const* d_in, const int* in_sizes, int n_in,
                              void* d_out, int out_size, void* d_ws, size_t ws_size,
                              hipStream_t stream)
{
    const float* x   = (const float*)d_in[0];
    const int*   ep  = (const int*)d_in[1];
    const int*   es  = (const int*)d_in[2];
    const int*   ev  = (const int*)d_in[3];
    const float* Wp  = (const float*)d_in[4];
    const float* bp  = (const float*)d_in[5];
    const float* Ws  = (const float*)d_in[6];
    const float* bs  = (const float*)d_in[7];
    const float* Wv  = (const float*)d_in[8];
    const float* bv  = (const float*)d_in[9];
    const float* pw1 = (const float*)d_in[10];
    const float* pb1 = (const float*)d_in[11];
    const float* pw2 = (const float*)d_in[12];
    const float* pb2 = (const float*)d_in[13];
    const float* cw1 = (const float*)d_in[14];
    const float* cb1 = (const float*)d_in[15];
    const float* cw2 = (const float*)d_in[16];
    const float* cb2 = (const float*)d_in[17];
    float* out = (float*)d_out;

    int gridN = (N_NODES + 255) / 256;

    const size_t H_BYTES   = 3ULL * N_NODES * 8 * 4;         // 48.0 MB
    const size_t P_BYTES   = 3ULL * N_EDGES * 4;             // 96.0 MB
    const size_t G_BYTES   = 3ULL * N_NODES * 16;            // 24.0 MB
    const size_t ACC_BYTES = 3ULL * NPAD * 5 * 4;            // 30.0 MB
    const size_t BHB_PAD   = ((3ULL * S_BLOCKS * NBKT + 3) / 4) * 4;   // uints
    const size_t SEGT      = 3ULL * NBKT * NSEGB;            // uints
    const size_t SEGP      = 3ULL * NSEGB * NBKT;            // uints
    const size_t META      = (BHB_PAD + SEGT + SEGP + 9ULL * NBKT) * 4 + 1024;
    const size_t NEED = H_BYTES + P_BYTES + G_BYTES + ACC_BYTES + META;

    if (ws_size >= NEED) {
        float* H       = (float*)d_ws;
        uint*  parts   = (uint*)((char*)d_ws + H_BYTES);
        uint4* G       = (uint4*)(parts + 3ULL * N_EDGES);
        float* accum   = (float*)((char*)G + G_BYTES);
        uint*  bhB     = (uint*)((char*)accum + ACC_BYTES);
        uint*  segtotB = bhB + BHB_PAD;                      // 16B-aligned
        uint*  segpreB = segtotB + SEGT;
        uint*  countsB = segpreB + SEGP;
        uint*  baseB   = countsB + 3 * NBKT;
        uint*  bendB   = baseB + 3 * NBKT;

        dim3 gridS(S_BLOCKS, 3);
        dim3 gridB1((NBKT + 255) / 256, NSEGB, 3);
        dim3 gridB2((NBKT + 255) / 256, 3);
        dim3 gridP2(NBKT, 3);

        k1_hx<<<gridN, 256, 0, stream>>>(x, Wp, Ws, Wv, H);
        pS_hist<<<gridS, SBLK, 0, stream>>>(ep, es, ev, bhB);
        kB1_segscan<<<gridB1, 256, 0, stream>>>(bhB, segtotB);
        kB2_counts<<<gridB2, 256, 0, stream>>>(segtotB, countsB);
        scanB<<<3, 512, 0, stream>>>(countsB, baseB, bendB);
        kB3_segpre<<<gridB2, 256, 0, stream>>>(segtotB, baseB, segpreB);
        pS_scatter<<<gridS, SBLK, 0, stream>>>(ep, es, ev, bhB, segpreB, parts);
        p2a_deg2<<<gridP2, 256, 0, stream>>>(parts, baseB, bendB, H, G);
        p2b_agg2<<<gridP2, 512, 0, stream>>>(parts, baseB, bendB, G,
                                             bp, bs, bv, accum);
        k6_mlp<<<gridN, 256, 0, stream>>>(accum, pw1, pb1, pw2, pb2,
                                          cw1, cb1, cw2, cb2, out);
    } else {
        // minimal fallback (round-0 pipeline, needs 66 MB)
        float* ws    = (float*)d_ws;
        float* h     = ws;
        float* deg   = h + 3L * N_NODES * 5;
        float* accum = deg + 3L * N_NODES;

        const int BLK = 256;
        int gridNf = (N_NODES + BLK - 1) / BLK;
        long totalE = 3L * N_EDGES;
        int gridE = (int)((totalE + BLK - 1) / BLK);

        k1_gemm_deginit<<<gridNf, BLK, 0, stream>>>(x, Wp, Ws, Wv, h, deg);
        k2_degree<<<gridE, BLK, 0, stream>>>(ep, es, ev, deg);
        k3_accum_init<<<gridNf, BLK, 0, stream>>>(h, deg, bp, bs, bv, accum);
        k4_scatter<<<gridE, BLK, 0, stream>>>(ep, es, ev, h, deg, accum);
        k5_mlp<<<gridNf, BLK, 0, stream>>>(accum, pw1, pb1, pw2, pb2, cw1, cb1, cw2, cb2, out);
    }
}